// Round 8
// baseline (423.605 us; speedup 1.0000x reference)
//
#include <hip/hip_runtime.h>
#include <hip/hip_bf16.h>
#include <stdint.h>

// GraphInterConnection P=16,B=4,C=256,N=256.  R17 = BISECT of R16's -70%
// regression: keep Wb XOR swizzle (bank conflicts 5.77M -> 0, verified),
// REMOVE s_setprio (suspect: m190 — setprio REGRESSES barrier-lockstep
// schedules; ours is 4-wave lockstep with 192 barriers/block; R16 steady
// 334us == R10's serial time => overlap destroyed by priority inversion).
// R15 design (verified 197us): 3 x 16KB rotating LDS buffers; per phase:
//   vmcnt(4) -> sched_barrier -> s_barrier -> sched_barrier -> issue
//   stage(p+2) -> compute(p).  No __syncthreads in the loop; stage latency
//   spans 2 compute phases.
//   corr[j,d]=sum_c tf_p[c,j]We[d,c]; A[j,i]=sum_d corr[j,d]tf_q[d,i]
//   S=softmax_i(A[j,:]); g_q[i]=sum_c Wg[c]tf_q[c,i]
//   mask[j]=sigmoid(sum_i S[j,i]g_q[i]);  W=mask*S
//   out[p,b,c,j]=(1/pn)*sum_q sum_i W[j,i]tf_q[c,i]   (fp32 output!)
// Precision: M1 3-chain split (corr hi/lo x tfT hi/lo), M2 1-chain (tf hi x W
// bf16 — W-bf16 proven at absmax 0.0039 in R8).

#define NP 16
#define NB 4
#define NC 256
#define NN 256
#define SLAB 65536

typedef __attribute__((ext_vector_type(8))) short bf16x8;
typedef __attribute__((ext_vector_type(4))) float f32x4;
typedef __attribute__((ext_vector_type(4))) float f4;

static __device__ __forceinline__ float b2f(unsigned short u) {
  union { unsigned u; float f; } x; x.u = ((unsigned)u) << 16; return x.f;
}
static __device__ __forceinline__ unsigned short f2b(float f) {
  unsigned u = __float_as_uint(f);
  u += 0x7fffu + ((u >> 16) & 1u);
  return (unsigned short)(u >> 16);
}
static __device__ __forceinline__ int is_bf16(const void* p) {
  const unsigned short* s = (const unsigned short*)p;
  int sane = 0;
  for (int i = 0; i < 64; ++i) {
    float av = fabsf(b2f(s[i]));
    sane += ((av == 0.0f) || (av > 8e-13f && av < 256.0f)) ? 1 : 0;
  }
  return sane >= 56;
}
static __device__ __forceinline__ f4 ld4(const void* p, size_t idx, int isb) {
  if (isb) {
    ushort4 v = *(const ushort4*)((const unsigned short*)p + idx);
    f4 r; r[0] = b2f(v.x); r[1] = b2f(v.y); r[2] = b2f(v.z); r[3] = b2f(v.w);
    return r;
  }
  return *(const f4*)((const float*)p + idx);
}
static __device__ __forceinline__ float read_pn(const void* p) {
  int iv = *(const int*)p;
  if (iv >= 1 && iv <= 65536) return (float)iv;
  float fv = *(const float*)p;
  if (fv >= 1.0f && fv <= 65536.0f) return fv;
  return 16.0f;
}
// async global->LDS, 16B per lane.  LDS dest must be WAVE-UNIFORM (HW adds
// lane*16); global src is per-lane.
static __device__ __forceinline__ void gld_lds16(const unsigned short* g,
                                                 unsigned short* l) {
  __builtin_amdgcn_global_load_lds(
      (const __attribute__((address_space(1))) unsigned int*)g,
      (__attribute__((address_space(3))) unsigned int*)l, 16, 0, 0);
}
// M1 chunk stage: 16 i-rows, hi (8KB) + lo (8KB) -> one 16KB rot buffer.
static __device__ __forceinline__ void stage1(const unsigned short* sh,
                                              const unsigned short* sl,
                                              int tid, int wave,
                                              unsigned short* dst) {
#pragma unroll
  for (int s = 0; s < 2; ++s) {
    const size_t f = (size_t)(s * 256 + tid);
    const int lb = (s * 256 + wave * 64) * 8;
    gld_lds16(sh + f * 8, dst + lb);
    gld_lds16(sl + f * 8, dst + 4096 + lb);
  }
}
// M2 chunk stage: 32 c-rows (16KB) -> one rot buffer.
static __device__ __forceinline__ void stage2(const unsigned short* sh,
                                              int tid, int wave,
                                              unsigned short* dst) {
#pragma unroll
  for (int s = 0; s < 4; ++s) {
    const size_t f = (size_t)(s * 256 + tid);
    const int lb = (s * 256 + wave * 64) * 8;
    gld_lds16(sh + f * 8, dst + lb);
  }
}

// ---- k_conv: temp -> th (bf16 hi, PRE-SWIZZLED); We -> weh/wel; Wg -> fp32 -
__global__ __launch_bounds__(256, 1)
void k_conv(const void* tv, const void* wev, const void* wgv,
            unsigned short* __restrict__ th,
            unsigned short* __restrict__ weh, unsigned short* __restrict__ wel,
            float* __restrict__ wgf)
{
  const int bx = blockIdx.x, tid = threadIdx.x;
  if (bx < 2048) {
    const int tb = is_bf16(tv);
    const size_t base = (size_t)bx * 2048 + tid * 8;   // linear element idx
    const int c  = (int)((base >> 8) & 255);
    const int kb = (int)((base >> 3) & 31);
    const size_t dst = (base & ~(size_t)255) + (size_t)((kb ^ (c & 15)) * 8);
    bf16x8 h;
#pragma unroll
    for (int s = 0; s < 2; ++s) {
      f4 v = ld4(tv, base + s * 4, tb);
#pragma unroll
      for (int k = 0; k < 4; ++k) h[s * 4 + k] = (short)f2b(v[k]);
    }
    *(bf16x8*)(th + dst) = h;
  } else if (bx < 2080) {
    const int eb = is_bf16(wev);
    const size_t base = (size_t)(bx - 2048) * 2048 + tid * 8;
    bf16x8 h, l;
#pragma unroll
    for (int s = 0; s < 2; ++s) {
      f4 v = ld4(wev, base + s * 4, eb);
#pragma unroll
      for (int k = 0; k < 4; ++k) {
        unsigned short hi = f2b(v[k]);
        h[s * 4 + k] = (short)hi;
        l[s * 4 + k] = (short)f2b(v[k] - b2f(hi));
      }
    }
    *(bf16x8*)(weh + base) = h;
    *(bf16x8*)(wel + base) = l;
  } else {
    if (tid < 64) {
      const int gb = is_bf16(wgv);
      f4 v = ld4(wgv, tid * 4, gb);
      *(f4*)(wgf + tid * 4) = v;
    }
  }
}

// ---- k_prep: transpose + tfT hi/lo (PRE-SWIZZLED) + g + corr hi/lo --------
__global__ __launch_bounds__(256, 1)
void k_prep(const void* __restrict__ tempv,
            const unsigned short* __restrict__ weh, const unsigned short* __restrict__ wel,
            const float* __restrict__ wgf,
            unsigned short* __restrict__ tfTh, unsigned short* __restrict__ tfTl,
            unsigned short* __restrict__ corrh, unsigned short* __restrict__ corrl,
            float* __restrict__ gws)
{
  __shared__ float smT[32 * 264];   // [row=i-local][c] fp32
  __shared__ float gpart[256];
  const int bx = blockIdx.x;
  const int pb = bx >> 3, cb = bx & 7;
  const int tid = threadIdx.x;
  const int lane = tid & 63, wave = tid >> 6;
  const int l15 = lane & 15, quad = lane >> 4;
  const int tb = is_bf16(tempv);

#pragma unroll
  for (int s = 0; s < 8; ++s) {
    f4 v = ld4(tempv, (size_t)pb * SLAB + (size_t)tid * NN + cb * 32 + s * 4, tb);
#pragma unroll
    for (int w = 0; w < 4; ++w) smT[(s * 4 + w) * 264 + tid] = v[w];
  }
  __syncthreads();

  {
#pragma unroll
    for (int s = 0; s < 4; ++s) {
      int f = s * 256 + tid;
      int row = f >> 5, kb = f & 31;
      bf16x8 vh, vl;
#pragma unroll
      for (int e = 0; e < 8; ++e) {
        float v = smT[row * 264 + kb * 8 + e];
        unsigned short hi = f2b(v);
        vh[e] = (short)hi;
        vl[e] = (short)f2b(v - b2f(hi));
      }
      size_t o = (size_t)pb * SLAB + (size_t)(cb * 32 + row) * NN
               + (size_t)((kb ^ (row & 15)) * 8);
      *(bf16x8*)(tfTh + o) = vh;
      *(bf16x8*)(tfTl + o) = vl;
    }
    const int row = tid >> 3, grp = tid & 7;
    float a = 0.f;
#pragma unroll
    for (int u = 0; u < 32; ++u) {
      int c = grp * 32 + u;
      a = fmaf(smT[row * 264 + c], wgf[c], a);
    }
    gpart[tid] = a;
  }
  __syncthreads();
  if (tid < 32) {
    float g = 0.f;
#pragma unroll
    for (int k = 0; k < 8; ++k) g += gpart[tid * 8 + k];
    gws[pb * NN + cb * 32 + tid] = g;
  }

  {
    const int jt = wave & 1, dh = wave >> 1;
    bf16x8 ah[8], al[8];
#pragma unroll
    for (int kk = 0; kk < 8; ++kk) {
#pragma unroll
      for (int e = 0; e < 8; ++e) {
        float v = smT[(jt * 16 + l15) * 264 + kk * 32 + quad * 8 + e];
        unsigned short hi = f2b(v);
        ah[kk][e] = (short)hi;
        al[kk][e] = (short)f2b(v - b2f(hi));
      }
    }
    for (int dt = 0; dt < 8; ++dt) {
      const int dbase = dh * 128 + dt * 16;
      f32x4 acc = {0.f, 0.f, 0.f, 0.f};
#pragma unroll
      for (int kk = 0; kk < 8; ++kk) {
        bf16x8 bh = *(const bf16x8*)(weh + (size_t)(dbase + l15) * NC + kk * 32 + quad * 8);
        bf16x8 bl = *(const bf16x8*)(wel + (size_t)(dbase + l15) * NC + kk * 32 + quad * 8);
        acc = __builtin_amdgcn_mfma_f32_16x16x32_bf16(al[kk], bh, acc, 0, 0, 0);
        acc = __builtin_amdgcn_mfma_f32_16x16x32_bf16(ah[kk], bl, acc, 0, 0, 0);
        acc = __builtin_amdgcn_mfma_f32_16x16x32_bf16(ah[kk], bh, acc, 0, 0, 0);
      }
#pragma unroll
      for (int r = 0; r < 4; ++r) {
        int j = cb * 32 + jt * 16 + quad * 4 + r;
        int d = dbase + l15;
        unsigned short hi = f2b(acc[r]);
        float lo = acc[r] - b2f(hi);
        size_t off = (size_t)pb * SLAB + (size_t)j * NC + d;
        corrh[off] = hi;
        corrl[off] = f2b(lo);
      }
    }
  }
}

// ---- k_main: counted-vmcnt pipelined MFMA attention ----------------------
// grid 512 = pb(64) x jt(4) x qh(2); 256 threads (wave -> 16 j rows)
// LDS 48KB: rot[3][16KB].  24 phases/q: 16 M1 (16 i-rows) + 8 M2 (32 c-rows).
// Phase: vmcnt(4); s_barrier; issue stage(p+2); compute(p).  Stage(g) lands
// in rot[g%3]; consumed at phase g (24%3==0 -> q-seamless).  NO setprio.
__global__ __launch_bounds__(256, 2)
void k_main(const unsigned short* __restrict__ th,
            const unsigned short* __restrict__ tfTh, const unsigned short* __restrict__ tfTl,
            const unsigned short* __restrict__ corrh, const unsigned short* __restrict__ corrl,
            const float* __restrict__ gws, const void* __restrict__ pnv,
            float* __restrict__ out)
{
  __shared__ unsigned short rot[3][8192];
  const int bx = blockIdx.x;
  const int pb = bx >> 3;
  const int b  = pb & 3;
  const int jt = (bx >> 1) & 3;
  const int qh = bx & 1;
  const int tid = threadIdx.x;
  const int lane = tid & 63, wave = tid >> 6;
  const int l15 = lane & 15, quad = lane >> 4;
  const int jbaseW = jt * 64 + wave * 16;

  const float inv = 1.0f / read_pn(pnv);

  // prologue: stages g=0,1 (first q, M1 chunks 0,1) -> rot0, rot1
  {
    const size_t s0 = (size_t)((qh * 8) * NB + b) * SLAB;
    stage1(tfTh + s0, tfTl + s0, tid, wave, rot[0]);
    stage1(tfTh + s0 + 4096, tfTl + s0 + 4096, tid, wave, rot[1]);
  }
  // resident corr A-frags (hi/lo), reused across all 8 q of this half
  bf16x8 chf[8], clf[8];
#pragma unroll
  for (int kk = 0; kk < 8; ++kk) {
    size_t off = (size_t)pb * SLAB + (size_t)(jbaseW + l15) * NC + kk * 32 + quad * 8;
    chf[kk] = *(const bf16x8*)(corrh + off);
    clf[kk] = *(const bf16x8*)(corrl + off);
  }

  const f32x4 fz = {0.f, 0.f, 0.f, 0.f};
  f32x4 outacc[16];
#pragma unroll
  for (int t = 0; t < 16; ++t) outacc[t] = fz;

  for (int qi = 0; qi < 8; ++qi) {
    const int q = qh * 8 + qi;
    const size_t slab  = (size_t)(q * NB + b) * SLAB;
    const size_t slabn = slab + (size_t)NB * SLAB;   // next q's slab

    f32x4 Aacc[16];
    float gqv[16];

    // ---- M1: 16 phases (16 i-rows each) ----
#pragma unroll
    for (int p = 0; p < 16; ++p) {
      asm volatile("s_waitcnt vmcnt(4)");
      __builtin_amdgcn_sched_barrier(0);
      __builtin_amdgcn_s_barrier();
      __builtin_amdgcn_sched_barrier(0);
      if (p == 15) {   // gq loads: older than stage(17), waited by softmax use
#pragma unroll
        for (int t = 0; t < 16; ++t)
          gqv[t] = gws[(q * NB + b) * NN + t * 16 + l15];
      }
      // issue stage(p+2): p<14 -> M1 chunk p+2; p=14,15 -> M2 chunks 0,1
      if (p < 14)
        stage1(tfTh + slab + (size_t)(p + 2) * 4096,
               tfTl + slab + (size_t)(p + 2) * 4096, tid, wave, rot[(p + 2) % 3]);
      else
        stage2(th + slab + (size_t)(p - 14) * 8192, tid, wave, rot[(p + 2) % 3]);
      // compute M1 chunk p from rot[p%3]
      const unsigned short* sgh = rot[p % 3];
      const unsigned short* sgl = sgh + 4096;
      f32x4 a = fz;
#pragma unroll
      for (int kk = 0; kk < 8; ++kk) {
        int src = l15 * 256 + (((kk * 4 + quad) ^ l15) * 8);
        bf16x8 bh = *(const bf16x8*)(sgh + src);
        bf16x8 bl = *(const bf16x8*)(sgl + src);
        a = __builtin_amdgcn_mfma_f32_16x16x32_bf16(clf[kk], bh, a, 0, 0, 0);
        a = __builtin_amdgcn_mfma_f32_16x16x32_bf16(chf[kk], bl, a, 0, 0, 0);
        a = __builtin_amdgcn_mfma_f32_16x16x32_bf16(chf[kk], bh, a, 0, 0, 0);
      }
      Aacc[p] = a;
    }

    // ---- softmax + gate (rot0 free: stages 16,17 sit in rot1,rot2) ----
    __builtin_amdgcn_s_barrier();     // all waves done reading rot0 (M1 c15)
    __builtin_amdgcn_sched_barrier(0);
    float sc4[4];
#pragma unroll
    for (int r = 0; r < 4; ++r) {
      float m = -1e30f;
#pragma unroll
      for (int t = 0; t < 16; ++t) m = fmaxf(m, Aacc[t][r]);
      m = fmaxf(m, __shfl_xor(m, 1)); m = fmaxf(m, __shfl_xor(m, 2));
      m = fmaxf(m, __shfl_xor(m, 4)); m = fmaxf(m, __shfl_xor(m, 8));
      float z = 0.f, s = 0.f;
#pragma unroll
      for (int t = 0; t < 16; ++t) {
        float e = __expf(Aacc[t][r] - m);
        Aacc[t][r] = e;
        z += e;
        s = fmaf(e, gqv[t], s);
      }
      z += __shfl_xor(z, 1); z += __shfl_xor(z, 2); z += __shfl_xor(z, 4); z += __shfl_xor(z, 8);
      s += __shfl_xor(s, 1); s += __shfl_xor(s, 2); s += __shfl_xor(s, 4); s += __shfl_xor(s, 8);
      float rz = 1.f / z;
      float mask = 1.f / (1.f + __expf(-s * rz));
      sc4[r] = mask * rz;
    }
    // W transpose via per-wave 4KB slice of rot0, two i-half rounds.
    // XOR-SWIZZLED: write block cb^jr, read block kb^l15 (R15's unswizzled
    // layout was a 16-way conflict: row stride 256B = 0 mod 32 banks).
    unsigned short* Wb = &rot[0][wave * 2048];
    bf16x8 wf[8];
#pragma unroll
    for (int r = 0; r < 4; ++r) {
      const int jr = quad * 4 + r;
#pragma unroll
      for (int t = 0; t < 8; ++t) {
        const int cb = t * 2 + (l15 >> 3);
        Wb[jr * 128 + ((cb ^ jr) * 8) + (l15 & 7)] = f2b(Aacc[t][r] * sc4[r]);
      }
    }
    __builtin_amdgcn_sched_barrier(0);
#pragma unroll
    for (int kk = 0; kk < 4; ++kk)
      wf[kk] = *(const bf16x8*)(Wb + l15 * 128 + (((kk * 4 + quad) ^ l15) * 8));
    __builtin_amdgcn_sched_barrier(0);
#pragma unroll
    for (int r = 0; r < 4; ++r) {
      const int jr = quad * 4 + r;
#pragma unroll
      for (int t = 8; t < 16; ++t) {
        const int cb = (t - 8) * 2 + (l15 >> 3);
        Wb[jr * 128 + ((cb ^ jr) * 8) + (l15 & 7)] = f2b(Aacc[t][r] * sc4[r]);
      }
    }
    __builtin_amdgcn_sched_barrier(0);
#pragma unroll
    for (int kk = 4; kk < 8; ++kk)
      wf[kk] = *(const bf16x8*)(Wb + l15 * 128 + ((((kk - 4) * 4 + quad) ^ l15) * 8));
    // wf reads must be architecturally complete before this wave reaches the
    // next barrier — after it, other waves issue stage(18) overwriting rot0.
    asm volatile("s_waitcnt lgkmcnt(0)");
    __builtin_amdgcn_sched_barrier(0);

    // ---- M2: 8 phases (32 c-rows each) ----
#pragma unroll
    for (int p = 16; p < 24; ++p) {
      if (p == 23 && qi == 7) { asm volatile("s_waitcnt vmcnt(0)"); }
      else                    { asm volatile("s_waitcnt vmcnt(4)"); }
      __builtin_amdgcn_sched_barrier(0);
      __builtin_amdgcn_s_barrier();   // also: all waves done with rot0 Wb
      __builtin_amdgcn_sched_barrier(0);
      if (qi < 7 || p < 22) {
        if (p < 22)
          stage2(th + slab + (size_t)(p - 14) * 8192, tid, wave, rot[(p + 2) % 3]);
        else
          stage1(tfTh + slabn + (size_t)(p - 22) * 4096,
                 tfTl + slabn + (size_t)(p - 22) * 4096, tid, wave, rot[(p + 2) % 3]);
      }
      // compute M2 chunk p-16 from rot[p%3]
      const unsigned short* sg = rot[p % 3];
#pragma unroll
      for (int ct = 0; ct < 2; ++ct) {
        const int tg = (p - 16) * 2 + ct;
#pragma unroll
        for (int kk = 0; kk < 8; ++kk) {
          int src = (ct * 16 + l15) * 256 + (((kk * 4 + quad) ^ l15) * 8);
          bf16x8 afr = *(const bf16x8*)(sg + src);
          outacc[tg] = __builtin_amdgcn_mfma_f32_16x16x32_bf16(afr, wf[kk], outacc[tg], 0, 0, 0);
        }
      }
    }
  }

  // ---- epilogue: fp32 atomic accumulate (two qh blocks per output) ----
#pragma unroll
  for (int t = 0; t < 16; ++t) {
#pragma unroll
    for (int r = 0; r < 4; ++r) {
      int c = t * 16 + quad * 4 + r;
      int j = jbaseW + l15;
      atomicAdd(out + ((size_t)pb * NC + c) * NN + j, outacc[t][r] * inv);
    }
  }
}

extern "C" void kernel_launch(void* const* d_in, const int* in_sizes, int n_in,
                              void* d_out, int out_size, void* d_ws, size_t ws_size,
                              hipStream_t stream) {
  const void* temp = nullptr; const void* We = nullptr;
  const void* Wg = nullptr;   const void* pn = nullptr;
  for (int i = 0; i < n_in; ++i) {
    switch (in_sizes[i]) {
      case 4194304: temp = d_in[i]; break;
      case 65536:   We   = d_in[i]; break;
      case 256:     Wg   = d_in[i]; break;
      case 1:       pn   = d_in[i]; break;
      default: break;
    }
  }
  if (!temp) temp = d_in[0];
  if (!We)   We   = d_in[1];
  if (!Wg)   Wg   = d_in[2];
  if (!pn)   pn   = d_in[3];

  char* ws = (char*)d_ws;
  unsigned short* th    = (unsigned short*)(ws);              //  8 MB  [pb] swz image
  unsigned short* tfTh  = (unsigned short*)(ws +  8388608);   //  8 MB  [pb] swz image hi
  unsigned short* tfTl  = (unsigned short*)(ws + 16777216);   //  8 MB  [pb] swz image lo
  unsigned short* corrh = (unsigned short*)(ws + 25165824);   //  8 MB  [pb][j][d] hi
  unsigned short* corrl = (unsigned short*)(ws + 33554432);   //  8 MB  [pb][j][d] lo
  unsigned short* weh   = (unsigned short*)(ws + 41943040);   // 128 KB
  unsigned short* wel   = (unsigned short*)(ws + 42074112);   // 128 KB
  float*          gws   = (float*)         (ws + 42205184);   //  64 KB
  float*          wgf   = (float*)         (ws + 42270720);   //   1 KB

  hipMemsetAsync(d_out, 0, (size_t)out_size * sizeof(float), stream);
  hipLaunchKernelGGL(k_conv, dim3(2081), dim3(256), 0, stream,
                     temp, We, Wg, th, weh, wel, wgf);
  hipLaunchKernelGGL(k_prep, dim3(512), dim3(256), 0, stream,
                     temp, weh, wel, wgf, tfTh, tfTl, corrh, corrl, gws);
  hipLaunchKernelGGL(k_main, dim3(512), dim3(256), 0, stream,
                     th, tfTh, tfTl, corrh, corrl, gws, pn, (float*)d_out);
}

// Round 9
// 291.293 us; speedup vs baseline: 1.4542x; 1.4542x over previous
//
#include <hip/hip_runtime.h>
#include <hip/hip_bf16.h>
#include <stdint.h>

// GraphInterConnection P=16,B=4,C=256,N=256.  R18 = R15 champion RESTORED
// (197us k_main) + pipeline depth 2 -> 3:
//   - rot[4] x 16KB (64KB LDS, still 2 blocks/CU); stage(p+3); vmcnt(8)
//     steady (tail qi=7: p22 vmcnt(4), p23 vmcnt(0)).  3 stages in flight.
//   - Wb = rot[3] (idle during softmax under mod-4 rotation: stages 16,17,18
//     occupy rot0,1,2; rot3 was just consumed by M1 phase 15).
// R16/R17 POST-MORTEM (both reverted): Wb XOR swizzle regressed 197->324us
// in BOTH variants — FETCH +160MB / WRITE +50MB at fixed VGPR=128 =>
// scratch spill from extra live temps in the register-critical softmax
// section.  The 5.77M bank conflicts it fixed cost only ~5us — keep R15's
// unswizzled Wb.  setprio: ~neutral-to-negative (lockstep schedule, m190).
// R15 design (verified): per phase: vmcnt(N) -> sched_barrier -> s_barrier
// -> sched_barrier -> issue stage(p+3) -> compute(p).  No __syncthreads in
// the loop; each stage's latency spans 3 compute phases.
//   corr[j,d]=sum_c tf_p[c,j]We[d,c]; A[j,i]=sum_d corr[j,d]tf_q[d,i]
//   S=softmax_i(A[j,:]); g_q[i]=sum_c Wg[c]tf_q[c,i]
//   mask[j]=sigmoid(sum_i S[j,i]g_q[i]);  W=mask*S
//   out[p,b,c,j]=(1/pn)*sum_q sum_i W[j,i]tf_q[c,i]   (fp32 output!)
// Precision: M1 3-chain split (corr hi/lo x tfT hi/lo), M2 1-chain (tf hi x W
// bf16 — W-bf16 proven at absmax 0.0039 in R8).

#define NP 16
#define NB 4
#define NC 256
#define NN 256
#define SLAB 65536

typedef __attribute__((ext_vector_type(8))) short bf16x8;
typedef __attribute__((ext_vector_type(4))) float f32x4;
typedef __attribute__((ext_vector_type(4))) float f4;

static __device__ __forceinline__ float b2f(unsigned short u) {
  union { unsigned u; float f; } x; x.u = ((unsigned)u) << 16; return x.f;
}
static __device__ __forceinline__ unsigned short f2b(float f) {
  unsigned u = __float_as_uint(f);
  u += 0x7fffu + ((u >> 16) & 1u);
  return (unsigned short)(u >> 16);
}
static __device__ __forceinline__ int is_bf16(const void* p) {
  const unsigned short* s = (const unsigned short*)p;
  int sane = 0;
  for (int i = 0; i < 64; ++i) {
    float av = fabsf(b2f(s[i]));
    sane += ((av == 0.0f) || (av > 8e-13f && av < 256.0f)) ? 1 : 0;
  }
  return sane >= 56;
}
static __device__ __forceinline__ f4 ld4(const void* p, size_t idx, int isb) {
  if (isb) {
    ushort4 v = *(const ushort4*)((const unsigned short*)p + idx);
    f4 r; r[0] = b2f(v.x); r[1] = b2f(v.y); r[2] = b2f(v.z); r[3] = b2f(v.w);
    return r;
  }
  return *(const f4*)((const float*)p + idx);
}
static __device__ __forceinline__ float read_pn(const void* p) {
  int iv = *(const int*)p;
  if (iv >= 1 && iv <= 65536) return (float)iv;
  float fv = *(const float*)p;
  if (fv >= 1.0f && fv <= 65536.0f) return fv;
  return 16.0f;
}
// async global->LDS, 16B per lane.  LDS dest must be WAVE-UNIFORM (HW adds
// lane*16); global src is per-lane.
static __device__ __forceinline__ void gld_lds16(const unsigned short* g,
                                                 unsigned short* l) {
  __builtin_amdgcn_global_load_lds(
      (const __attribute__((address_space(1))) unsigned int*)g,
      (__attribute__((address_space(3))) unsigned int*)l, 16, 0, 0);
}
// M1 chunk stage: 16 i-rows, hi (8KB) + lo (8KB) -> one 16KB rot buffer.
static __device__ __forceinline__ void stage1(const unsigned short* sh,
                                              const unsigned short* sl,
                                              int tid, int wave,
                                              unsigned short* dst) {
#pragma unroll
  for (int s = 0; s < 2; ++s) {
    const size_t f = (size_t)(s * 256 + tid);
    const int lb = (s * 256 + wave * 64) * 8;
    gld_lds16(sh + f * 8, dst + lb);
    gld_lds16(sl + f * 8, dst + 4096 + lb);
  }
}
// M2 chunk stage: 32 c-rows (16KB) -> one rot buffer.
static __device__ __forceinline__ void stage2(const unsigned short* sh,
                                              int tid, int wave,
                                              unsigned short* dst) {
#pragma unroll
  for (int s = 0; s < 4; ++s) {
    const size_t f = (size_t)(s * 256 + tid);
    const int lb = (s * 256 + wave * 64) * 8;
    gld_lds16(sh + f * 8, dst + lb);
  }
}

// ---- k_conv: temp -> th (bf16 hi, PRE-SWIZZLED); We -> weh/wel; Wg -> fp32 -
__global__ __launch_bounds__(256, 1)
void k_conv(const void* tv, const void* wev, const void* wgv,
            unsigned short* __restrict__ th,
            unsigned short* __restrict__ weh, unsigned short* __restrict__ wel,
            float* __restrict__ wgf)
{
  const int bx = blockIdx.x, tid = threadIdx.x;
  if (bx < 2048) {
    const int tb = is_bf16(tv);
    const size_t base = (size_t)bx * 2048 + tid * 8;   // linear element idx
    const int c  = (int)((base >> 8) & 255);
    const int kb = (int)((base >> 3) & 31);
    const size_t dst = (base & ~(size_t)255) + (size_t)((kb ^ (c & 15)) * 8);
    bf16x8 h;
#pragma unroll
    for (int s = 0; s < 2; ++s) {
      f4 v = ld4(tv, base + s * 4, tb);
#pragma unroll
      for (int k = 0; k < 4; ++k) h[s * 4 + k] = (short)f2b(v[k]);
    }
    *(bf16x8*)(th + dst) = h;
  } else if (bx < 2080) {
    const int eb = is_bf16(wev);
    const size_t base = (size_t)(bx - 2048) * 2048 + tid * 8;
    bf16x8 h, l;
#pragma unroll
    for (int s = 0; s < 2; ++s) {
      f4 v = ld4(wev, base + s * 4, eb);
#pragma unroll
      for (int k = 0; k < 4; ++k) {
        unsigned short hi = f2b(v[k]);
        h[s * 4 + k] = (short)hi;
        l[s * 4 + k] = (short)f2b(v[k] - b2f(hi));
      }
    }
    *(bf16x8*)(weh + base) = h;
    *(bf16x8*)(wel + base) = l;
  } else {
    if (tid < 64) {
      const int gb = is_bf16(wgv);
      f4 v = ld4(wgv, tid * 4, gb);
      *(f4*)(wgf + tid * 4) = v;
    }
  }
}

// ---- k_prep: transpose + tfT hi/lo (PRE-SWIZZLED) + g + corr hi/lo --------
__global__ __launch_bounds__(256, 1)
void k_prep(const void* __restrict__ tempv,
            const unsigned short* __restrict__ weh, const unsigned short* __restrict__ wel,
            const float* __restrict__ wgf,
            unsigned short* __restrict__ tfTh, unsigned short* __restrict__ tfTl,
            unsigned short* __restrict__ corrh, unsigned short* __restrict__ corrl,
            float* __restrict__ gws)
{
  __shared__ float smT[32 * 264];   // [row=i-local][c] fp32
  __shared__ float gpart[256];
  const int bx = blockIdx.x;
  const int pb = bx >> 3, cb = bx & 7;
  const int tid = threadIdx.x;
  const int lane = tid & 63, wave = tid >> 6;
  const int l15 = lane & 15, quad = lane >> 4;
  const int tb = is_bf16(tempv);

#pragma unroll
  for (int s = 0; s < 8; ++s) {
    f4 v = ld4(tempv, (size_t)pb * SLAB + (size_t)tid * NN + cb * 32 + s * 4, tb);
#pragma unroll
    for (int w = 0; w < 4; ++w) smT[(s * 4 + w) * 264 + tid] = v[w];
  }
  __syncthreads();

  {
#pragma unroll
    for (int s = 0; s < 4; ++s) {
      int f = s * 256 + tid;
      int row = f >> 5, kb = f & 31;
      bf16x8 vh, vl;
#pragma unroll
      for (int e = 0; e < 8; ++e) {
        float v = smT[row * 264 + kb * 8 + e];
        unsigned short hi = f2b(v);
        vh[e] = (short)hi;
        vl[e] = (short)f2b(v - b2f(hi));
      }
      size_t o = (size_t)pb * SLAB + (size_t)(cb * 32 + row) * NN
               + (size_t)((kb ^ (row & 15)) * 8);
      *(bf16x8*)(tfTh + o) = vh;
      *(bf16x8*)(tfTl + o) = vl;
    }
    const int row = tid >> 3, grp = tid & 7;
    float a = 0.f;
#pragma unroll
    for (int u = 0; u < 32; ++u) {
      int c = grp * 32 + u;
      a = fmaf(smT[row * 264 + c], wgf[c], a);
    }
    gpart[tid] = a;
  }
  __syncthreads();
  if (tid < 32) {
    float g = 0.f;
#pragma unroll
    for (int k = 0; k < 8; ++k) g += gpart[tid * 8 + k];
    gws[pb * NN + cb * 32 + tid] = g;
  }

  {
    const int jt = wave & 1, dh = wave >> 1;
    bf16x8 ah[8], al[8];
#pragma unroll
    for (int kk = 0; kk < 8; ++kk) {
#pragma unroll
      for (int e = 0; e < 8; ++e) {
        float v = smT[(jt * 16 + l15) * 264 + kk * 32 + quad * 8 + e];
        unsigned short hi = f2b(v);
        ah[kk][e] = (short)hi;
        al[kk][e] = (short)f2b(v - b2f(hi));
      }
    }
    for (int dt = 0; dt < 8; ++dt) {
      const int dbase = dh * 128 + dt * 16;
      f32x4 acc = {0.f, 0.f, 0.f, 0.f};
#pragma unroll
      for (int kk = 0; kk < 8; ++kk) {
        bf16x8 bh = *(const bf16x8*)(weh + (size_t)(dbase + l15) * NC + kk * 32 + quad * 8);
        bf16x8 bl = *(const bf16x8*)(wel + (size_t)(dbase + l15) * NC + kk * 32 + quad * 8);
        acc = __builtin_amdgcn_mfma_f32_16x16x32_bf16(al[kk], bh, acc, 0, 0, 0);
        acc = __builtin_amdgcn_mfma_f32_16x16x32_bf16(ah[kk], bl, acc, 0, 0, 0);
        acc = __builtin_amdgcn_mfma_f32_16x16x32_bf16(ah[kk], bh, acc, 0, 0, 0);
      }
#pragma unroll
      for (int r = 0; r < 4; ++r) {
        int j = cb * 32 + jt * 16 + quad * 4 + r;
        int d = dbase + l15;
        unsigned short hi = f2b(acc[r]);
        float lo = acc[r] - b2f(hi);
        size_t off = (size_t)pb * SLAB + (size_t)j * NC + d;
        corrh[off] = hi;
        corrl[off] = f2b(lo);
      }
    }
  }
}

// ---- k_main: 3-deep counted-vmcnt pipelined MFMA attention ---------------
// grid 512 = pb(64) x jt(4) x qh(2); 256 threads (wave -> 16 j rows)
// LDS 64KB: rot[4][16KB].  24 phases/q: 16 M1 (16 i-rows) + 8 M2 (32 c-rows).
// Phase: vmcnt(8); s_barrier; issue stage(p+3); compute(p).  Stage(g) lands
// in rot[g%4]; consumed at phase g (24%4==0 -> q-seamless).  NO setprio.
__global__ __launch_bounds__(256, 2)
void k_main(const unsigned short* __restrict__ th,
            const unsigned short* __restrict__ tfTh, const unsigned short* __restrict__ tfTl,
            const unsigned short* __restrict__ corrh, const unsigned short* __restrict__ corrl,
            const float* __restrict__ gws, const void* __restrict__ pnv,
            float* __restrict__ out)
{
  __shared__ unsigned short rot[4][8192];
  const int bx = blockIdx.x;
  const int pb = bx >> 3;
  const int b  = pb & 3;
  const int jt = (bx >> 1) & 3;
  const int qh = bx & 1;
  const int tid = threadIdx.x;
  const int lane = tid & 63, wave = tid >> 6;
  const int l15 = lane & 15, quad = lane >> 4;
  const int jbaseW = jt * 64 + wave * 16;

  const float inv = 1.0f / read_pn(pnv);

  // prologue: stages g=0,1,2 (first q, M1 chunks 0,1,2) -> rot0..rot2
  {
    const size_t s0 = (size_t)((qh * 8) * NB + b) * SLAB;
    stage1(tfTh + s0, tfTl + s0, tid, wave, rot[0]);
    stage1(tfTh + s0 + 4096, tfTl + s0 + 4096, tid, wave, rot[1]);
    stage1(tfTh + s0 + 8192, tfTl + s0 + 8192, tid, wave, rot[2]);
  }
  // resident corr A-frags (hi/lo), reused across all 8 q of this half
  bf16x8 chf[8], clf[8];
#pragma unroll
  for (int kk = 0; kk < 8; ++kk) {
    size_t off = (size_t)pb * SLAB + (size_t)(jbaseW + l15) * NC + kk * 32 + quad * 8;
    chf[kk] = *(const bf16x8*)(corrh + off);
    clf[kk] = *(const bf16x8*)(corrl + off);
  }

  const f32x4 fz = {0.f, 0.f, 0.f, 0.f};
  f32x4 outacc[16];
#pragma unroll
  for (int t = 0; t < 16; ++t) outacc[t] = fz;

  for (int qi = 0; qi < 8; ++qi) {
    const int q = qh * 8 + qi;
    const size_t slab  = (size_t)(q * NB + b) * SLAB;
    const size_t slabn = slab + (size_t)NB * SLAB;   // next q's slab

    f32x4 Aacc[16];
    float gqv[16];

    // ---- M1: 16 phases (16 i-rows each) ----
#pragma unroll
    for (int p = 0; p < 16; ++p) {
      asm volatile("s_waitcnt vmcnt(8)");
      __builtin_amdgcn_sched_barrier(0);
      __builtin_amdgcn_s_barrier();
      __builtin_amdgcn_sched_barrier(0);
      if (p == 15) {   // gq loads: waited by softmax use (drains stages 16,17)
#pragma unroll
        for (int t = 0; t < 16; ++t)
          gqv[t] = gws[(q * NB + b) * NN + t * 16 + l15];
      }
      // issue stage(p+3): p<13 -> M1 chunk p+3; p=13,14,15 -> M2 chunks 0,1,2
      if (p < 13)
        stage1(tfTh + slab + (size_t)(p + 3) * 4096,
               tfTl + slab + (size_t)(p + 3) * 4096, tid, wave, rot[(p + 3) & 3]);
      else
        stage2(th + slab + (size_t)(p - 13) * 8192, tid, wave, rot[(p + 3) & 3]);
      // compute M1 chunk p from rot[p&3]
      const unsigned short* sgh = rot[p & 3];
      const unsigned short* sgl = sgh + 4096;
      f32x4 a = fz;
#pragma unroll
      for (int kk = 0; kk < 8; ++kk) {
        int src = l15 * 256 + (((kk * 4 + quad) ^ l15) * 8);
        bf16x8 bh = *(const bf16x8*)(sgh + src);
        bf16x8 bl = *(const bf16x8*)(sgl + src);
        a = __builtin_amdgcn_mfma_f32_16x16x32_bf16(clf[kk], bh, a, 0, 0, 0);
        a = __builtin_amdgcn_mfma_f32_16x16x32_bf16(chf[kk], bl, a, 0, 0, 0);
        a = __builtin_amdgcn_mfma_f32_16x16x32_bf16(chf[kk], bh, a, 0, 0, 0);
      }
      Aacc[p] = a;
    }

    // ---- softmax + gate.  In-flight stages 16,17,18 -> rot0,rot1,rot2;
    // rot3 (just consumed by M1 phase 15) is free -> Wb lives there. ----
    __builtin_amdgcn_s_barrier();     // all waves done reading rot3 (M1 c15)
    __builtin_amdgcn_sched_barrier(0);
    float sc4[4];
#pragma unroll
    for (int r = 0; r < 4; ++r) {
      float m = -1e30f;
#pragma unroll
      for (int t = 0; t < 16; ++t) m = fmaxf(m, Aacc[t][r]);
      m = fmaxf(m, __shfl_xor(m, 1)); m = fmaxf(m, __shfl_xor(m, 2));
      m = fmaxf(m, __shfl_xor(m, 4)); m = fmaxf(m, __shfl_xor(m, 8));
      float z = 0.f, s = 0.f;
#pragma unroll
      for (int t = 0; t < 16; ++t) {
        float e = __expf(Aacc[t][r] - m);
        Aacc[t][r] = e;
        z += e;
        s = fmaf(e, gqv[t], s);
      }
      z += __shfl_xor(z, 1); z += __shfl_xor(z, 2); z += __shfl_xor(z, 4); z += __shfl_xor(z, 8);
      s += __shfl_xor(s, 1); s += __shfl_xor(s, 2); s += __shfl_xor(s, 4); s += __shfl_xor(s, 8);
      float rz = 1.f / z;
      float mask = 1.f / (1.f + __expf(-s * rz));
      sc4[r] = mask * rz;
    }
    // W transpose via per-wave 4KB slice of rot3, two i-half rounds (same-
    // wave DS order; sched_barrier prevents compiler reorder).  R15 layout —
    // do NOT swizzle (R16/R17: spill regression ≫ conflict cost).
    unsigned short* Wb = &rot[3][wave * 2048];
    bf16x8 wf[8];
#pragma unroll
    for (int r = 0; r < 4; ++r) {
      const int jr = quad * 4 + r;
#pragma unroll
      for (int t = 0; t < 8; ++t)
        Wb[jr * 128 + t * 16 + l15] = f2b(Aacc[t][r] * sc4[r]);
    }
    __builtin_amdgcn_sched_barrier(0);
#pragma unroll
    for (int kk = 0; kk < 4; ++kk)
      wf[kk] = *(const bf16x8*)(Wb + l15 * 128 + ((kk * 4 + quad) * 8));
    __builtin_amdgcn_sched_barrier(0);
#pragma unroll
    for (int r = 0; r < 4; ++r) {
      const int jr = quad * 4 + r;
#pragma unroll
      for (int t = 8; t < 16; ++t)
        Wb[jr * 128 + (t - 8) * 16 + l15] = f2b(Aacc[t][r] * sc4[r]);
    }
    __builtin_amdgcn_sched_barrier(0);
#pragma unroll
    for (int kk = 4; kk < 8; ++kk)
      wf[kk] = *(const bf16x8*)(Wb + l15 * 128 + (((kk - 4) * 4 + quad) * 8));
    // wf reads must be architecturally complete before this wave reaches the
    // next barrier — after it, other waves issue stage(19) overwriting rot3.
    asm volatile("s_waitcnt lgkmcnt(0)");
    __builtin_amdgcn_sched_barrier(0);

    // ---- M2: 8 phases (32 c-rows each) ----
#pragma unroll
    for (int p = 16; p < 24; ++p) {
      if (qi == 7 && p == 23)      { asm volatile("s_waitcnt vmcnt(0)"); }
      else if (qi == 7 && p == 22) { asm volatile("s_waitcnt vmcnt(4)"); }
      else                         { asm volatile("s_waitcnt vmcnt(8)"); }
      __builtin_amdgcn_sched_barrier(0);
      __builtin_amdgcn_s_barrier();   // also: all waves done with rot3 Wb
      __builtin_amdgcn_sched_barrier(0);
      // issue stage(p+3): p<=20 -> M2 chunks 3..7; p=21,22,23 -> next q's
      // M1 chunks 0,1,2 (skip on last q)
      if (p <= 20)
        stage2(th + slab + (size_t)(p - 13) * 8192, tid, wave, rot[(p + 3) & 3]);
      else if (qi < 7)
        stage1(tfTh + slabn + (size_t)(p - 21) * 4096,
               tfTl + slabn + (size_t)(p - 21) * 4096, tid, wave, rot[(p + 3) & 3]);
      // compute M2 chunk p-16 from rot[p&3]
      const unsigned short* sg = rot[p & 3];
#pragma unroll
      for (int ct = 0; ct < 2; ++ct) {
        const int tg = (p - 16) * 2 + ct;
#pragma unroll
        for (int kk = 0; kk < 8; ++kk) {
          int src = (ct * 16 + l15) * 256 + (((kk * 4 + quad) ^ l15) * 8);
          bf16x8 afr = *(const bf16x8*)(sg + src);
          outacc[tg] = __builtin_amdgcn_mfma_f32_16x16x32_bf16(afr, wf[kk], outacc[tg], 0, 0, 0);
        }
      }
    }
  }

  // ---- epilogue: fp32 atomic accumulate (two qh blocks per output) ----
#pragma unroll
  for (int t = 0; t < 16; ++t) {
#pragma unroll
    for (int r = 0; r < 4; ++r) {
      int c = t * 16 + quad * 4 + r;
      int j = jbaseW + l15;
      atomicAdd(out + ((size_t)pb * NC + c) * NN + j, outacc[t][r] * inv);
    }
  }
}

extern "C" void kernel_launch(void* const* d_in, const int* in_sizes, int n_in,
                              void* d_out, int out_size, void* d_ws, size_t ws_size,
                              hipStream_t stream) {
  const void* temp = nullptr; const void* We = nullptr;
  const void* Wg = nullptr;   const void* pn = nullptr;
  for (int i = 0; i < n_in; ++i) {
    switch (in_sizes[i]) {
      case 4194304: temp = d_in[i]; break;
      case 65536:   We   = d_in[i]; break;
      case 256:     Wg   = d_in[i]; break;
      case 1:       pn   = d_in[i]; break;
      default: break;
    }
  }
  if (!temp) temp = d_in[0];
  if (!We)   We   = d_in[1];
  if (!Wg)   Wg   = d_in[2];
  if (!pn)   pn   = d_in[3];

  char* ws = (char*)d_ws;
  unsigned short* th    = (unsigned short*)(ws);              //  8 MB  [pb] swz image
  unsigned short* tfTh  = (unsigned short*)(ws +  8388608);   //  8 MB  [pb] swz image hi
  unsigned short* tfTl  = (unsigned short*)(ws + 16777216);   //  8 MB  [pb] swz image lo
  unsigned short* corrh = (unsigned short*)(ws + 25165824);   //  8 MB  [pb][j][d] hi
  unsigned short* corrl = (unsigned short*)(ws + 33554432);   //  8 MB  [pb][j][d] lo
  unsigned short* weh   = (unsigned short*)(ws + 41943040);   // 128 KB
  unsigned short* wel   = (unsigned short*)(ws + 42074112);   // 128 KB
  float*          gws   = (float*)         (ws + 42205184);   //  64 KB
  float*          wgf   = (float*)         (ws + 42270720);   //   1 KB

  hipMemsetAsync(d_out, 0, (size_t)out_size * sizeof(float), stream);
  hipLaunchKernelGGL(k_conv, dim3(2081), dim3(256), 0, stream,
                     temp, We, Wg, th, weh, wel, wgf);
  hipLaunchKernelGGL(k_prep, dim3(512), dim3(256), 0, stream,
                     temp, weh, wel, wgf, tfTh, tfTl, corrh, corrl, gws);
  hipLaunchKernelGGL(k_main, dim3(512), dim3(256), 0, stream,
                     th, tfTh, tfTl, corrh, corrl, gws, pn, (float*)d_out);
}